// Round 8
// baseline (412.496 us; speedup 1.0000x reference)
//
#include <hip/hip_runtime.h>

// Problem constants
#define E_DIM 1024
#define H_NUM 16
#define D_HEAD 64
#define SEQ 2048
#define BATCH 2
#define NTOK 4096      // BATCH*SEQ
#define R_LORA 128
#define Q3 3072        // 3*E_DIM
#define SCALE_LOG2E 0.18033688011112042f  // (1/sqrt(64)) * log2(e), folded into K

typedef float floatx4 __attribute__((ext_vector_type(4)));
typedef __bf16 bf16x8 __attribute__((ext_vector_type(8)));
typedef __bf16 bf16x4 __attribute__((ext_vector_type(4)));
typedef bf16x8 bf16x8_al __attribute__((may_alias));
typedef bf16x4 bf16x4_al __attribute__((may_alias));

// async global->LDS, 16B per lane; lds dst must be wave-uniform (HW adds lane*16)
__device__ __forceinline__ void async_cp16(const void* g, void* l) {
  __builtin_amdgcn_global_load_lds(
      (__attribute__((address_space(1))) unsigned int*)(size_t)g,
      (__attribute__((address_space(3))) unsigned int*)l, 16, 0, 0);
}

// ---------------- fused prep kernel (one launch) ----------------
// [0,4096) x->xb | [4096,7168) weff rows (into wtot) | [7168,7552) binb
// [7552,7584) aeffT (fold+transpose) | [7584,8608) wo
__global__ __launch_bounds__(256) void prep_all(const float* __restrict__ x,
                                                const float* __restrict__ Wi,
                                                const float* __restrict__ Bl,
                                                const float* __restrict__ Ai,
                                                const float* __restrict__ Wo,
                                                __bf16* __restrict__ xb,
                                                __bf16* __restrict__ wtot,
                                                __bf16* __restrict__ binb,
                                                __bf16* __restrict__ aeffT,
                                                __bf16* __restrict__ wob) {
  __shared__ __bf16 tile[64][65];
  const int blk = blockIdx.x, t = threadIdx.x;
  if (blk < 4096) {                       // x (4096x1024 fp32) -> xb bf16 (contig)
    int idx = (blk * 256 + t) * 4;
    float4 v = *(const float4*)(x + idx);
    bf16x4 o = {(__bf16)v.x, (__bf16)v.y, (__bf16)v.z, (__bf16)v.w};
    *(bf16x4_al*)(xb + idx) = o;
  } else if (blk < 7168) {                // weff row j: fold 3 E-blocks of W_in -> wtot
    int j = blk - 4096, e = t * 4;
    const float* r = Wi + (size_t)j * Q3;
    float4 a = *(const float4*)(r + e);
    float4 b = *(const float4*)(r + e + 1024);
    float4 c = *(const float4*)(r + e + 2048);
    bf16x4 o = {(__bf16)(a.x + b.x + c.x), (__bf16)(a.y + b.y + c.y),
                (__bf16)(a.z + b.z + c.z), (__bf16)(a.w + b.w + c.w)};
    *(bf16x4_al*)(wtot + (size_t)j * E_DIM + e) = o;
  } else if (blk < 7552) {                // binb: B_in cast, dense [3072][128]
    int idx = (blk - 7168) * 256 + t;     // quad id over 3072x32
    int j = idx >> 5, cq = (idx & 31) * 4;
    float4 v = *(const float4*)(Bl + (size_t)j * R_LORA + cq);
    bf16x4 o = {(__bf16)v.x, (__bf16)v.y, (__bf16)v.z, (__bf16)v.w};
    *(bf16x4_al*)(binb + (size_t)j * R_LORA + cq) = o;
  } else if (blk < 7584) {                // aeffT[e][r] = fold of A_in, via LDS transpose
    int b2 = blk - 7552;
    int r0 = (b2 & 1) * 64, e0 = (b2 >> 1) * 64;
    int c = t & 63, r4 = t >> 6;
#pragma unroll
    for (int i = 0; i < 16; i++) {
      int row = r4 + i * 4;  // local r
      const float* rp = Ai + (size_t)(r0 + row) * Q3 + e0 + c;
      tile[row][c] = (__bf16)(rp[0] + rp[1024] + rp[2048]);
    }
    __syncthreads();
#pragma unroll
    for (int i = 0; i < 16; i++) {
      int er = r4 + i * 4;  // local e
      aeffT[(size_t)(e0 + er) * R_LORA + r0 + c] = tile[c][er];
    }
  } else {                                // wo cast
    int idx = ((blk - 7584) * 256 + t) * 4;
    float4 v = *(const float4*)(Wo + idx);
    bf16x4 o = {(__bf16)v.x, (__bf16)v.y, (__bf16)v.z, (__bf16)v.w};
    *(bf16x4_al*)(wob + idx) = o;
  }
}

// ---------------- TMx128 MFMA GEMM: D[m][n] = sum_k A[m][k]*B[n][k] ----------------
// TM=128: 4 waves in 2x2, acc[4][4]. TM=64: waves 1x4 (share A rows), acc[4][2].
// EPI 0: fp32 store, ldc=1024 (out-proj)
// EPI 1: qkv scatter; Q,K -> [bh][s][d] (K pre-scaled by SCALE_LOG2E); V -> V^T b64
// EPI 3: wtot in-place: o0 += acc*(1/128) (LoRA weight fold)
template <int TM, int KTOT, int LDA, int LDB, int EPI>
__global__ __launch_bounds__(256) void gemm_mfma(const __bf16* A, const __bf16* Bm,
                                                 float* fOut, __bf16* o0, __bf16* o1,
                                                 __bf16* o2) {
  constexpr int NSEG_A = TM / 16;       // 8 or 4
  constexpr int NSEG = NSEG_A + 8;      // 16 or 12
  constexpr int SPW = NSEG / 4;         // 4 or 3
  constexpr int NJ = (TM == 128) ? 4 : 2;
  __shared__ __bf16 lds[NSEG * 512];
  const int t = threadIdx.x;
  const int wave = t >> 6, lane = t & 63;
  const int lr = lane & 15, lq = lane >> 4;
  const int m0 = blockIdx.x * TM, n0 = blockIdx.y * 128;
  const int aw = (TM == 128) ? (wave & 1) * 4 : 0;          // A frag base seg
  const int bw = (TM == 128) ? (wave >> 1) * 4 : wave * 2;  // B frag base seg

  floatx4 acc[4][NJ] = {};

  for (int kk = 0; kk < KTOT; kk += 32) {
    __syncthreads();  // prior frag reads done before overwrite
#pragma unroll
    for (int ii = 0; ii < SPW; ii++) {
      int s = wave * SPW + ii;
      const __bf16* src =
          (s < NSEG_A)
              ? A + (size_t)(m0 + s * 16 + lr) * LDA + kk + lq * 8
              : Bm + (size_t)(n0 + (s - NSEG_A) * 16 + lr) * LDB + kk + lq * 8;
      async_cp16(src, lds + s * 512);
    }
    __syncthreads();  // drains vmcnt -> staging visible
    bf16x8 af[4], bfr[NJ];
#pragma unroll
    for (int i = 0; i < 4; i++)
      af[i] = *(const bf16x8_al*)(lds + (aw + i) * 512 + lane * 8);
#pragma unroll
    for (int j = 0; j < NJ; j++)
      bfr[j] = *(const bf16x8_al*)(lds + (NSEG_A + bw + j) * 512 + lane * 8);
#pragma unroll
    for (int i = 0; i < 4; i++)
#pragma unroll
      for (int j = 0; j < NJ; j++)
        acc[i][j] = __builtin_amdgcn_mfma_f32_16x16x32_bf16(af[i], bfr[j], acc[i][j], 0, 0, 0);
  }

#pragma unroll
  for (int i = 0; i < 4; i++)
#pragma unroll
    for (int j = 0; j < NJ; j++) {
      const int row0 = m0 + ((TM == 128) ? (wave & 1) * 64 : 0) + i * 16 + lq * 4;
      const int col = n0 + ((TM == 128) ? (wave >> 1) * 64 : wave * 32) + j * 16 + lr;
      if (EPI == 0) {
#pragma unroll
        for (int r = 0; r < 4; r++)
          fOut[(size_t)(row0 + r) * 1024 + col] = acc[i][j][r];
      } else if (EPI == 3) {
#pragma unroll
        for (int r = 0; r < 4; r++) {
          size_t off = (size_t)(row0 + r) * 1024 + col;
          o0[off] = (__bf16)((float)o0[off] + acc[i][j][r] * (1.0f / 128.0f));
        }
      } else {
        int part = col >> 10, e = col & 1023, h = e >> 6, d = e & 63;
        int b = row0 >> 11, s = row0 & 2047;
        if (part == 2) {
          // V^T [bh][d][s]: 4 consecutive s in one lane -> packed b64 store
          bf16x4 pv;
#pragma unroll
          for (int r = 0; r < 4; r++) pv[r] = (__bf16)acc[i][j][r];
          *(bf16x4_al*)(o2 + ((size_t)(b * H_NUM + h) * D_HEAD + d) * SEQ + s) = pv;
        } else {
#pragma unroll
          for (int r = 0; r < 4; r++) {
            float v = acc[i][j][r];
            if (part == 1) v *= SCALE_LOG2E;  // fold softmax scale + log2e into K
            size_t off = ((size_t)(b * H_NUM + h) * SEQ + (s + r)) * D_HEAD + d;
            (part == 0 ? o0 : o1)[off] = (__bf16)v;
          }
        }
      }
    }
}

// ---------------- flash attention v8: global->register frags, barrier-free ----------------
// 64 q-rows/block (16/wave). K and V^T fragments are loaded DIRECTLY from global
// into registers (the MFMA frag layout is 16 contiguous bytes per lane) — no LDS
// staging, no barriers, no cross-wave coupling at all. Only LDS use: the
// wave-private 1KB P round-trip (XOR-swizzled, b64 write / b128 A-frag read).
// Max-free softmax: K pre-scaled by (1/8)*log2e -> p = exp2(s). TLP + unroll-2
// ILP hide global latency (L2-resident K/V: 512KB/head).
__global__ __launch_bounds__(256) void attn_kernel(const __bf16* __restrict__ Q,
                                                   const __bf16* __restrict__ K,
                                                   const __bf16* __restrict__ Vt,
                                                   __bf16* __restrict__ O) {
  __shared__ __bf16 pls[4096];  // 4 waves x 1024 (8 KB total)
  const int t = threadIdx.x, wave = t >> 6, lane = t & 63;
  const int lr = lane & 15, lq = lane >> 4;
  __bf16* plsw = pls + wave * 1024;
  const int bh = blockIdx.y, q0 = blockIdx.x * 64;
  const size_t hbase = (size_t)bh * SEQ * D_HEAD;
  const __bf16* Kp = K + hbase;
  const __bf16* vtb = Vt + (size_t)bh * D_HEAD * SEQ;
  const int row7 = lr & 7;

  // Q frags (B-operand: rows q = q0+wave*16+lr)
  bf16x8 qf0, qf1;
  {
    const __bf16* qp = Q + hbase + (size_t)(q0 + wave * 16 + lr) * D_HEAD + lq * 8;
    qf0 = *(const bf16x8_al*)qp;
    qf1 = *(const bf16x8_al*)(qp + 32);
  }

  floatx4 oacc[4] = {};
  float lsum = 0.0f;

#pragma unroll 2
  for (int kt = 0; kt < SEQ; kt += 64) {
    // V^T B-frags for this tile: dep-free, issue early (vf[jd*2+kc])
    bf16x8 vf[8];
#pragma unroll
    for (int jd = 0; jd < 4; jd++)
#pragma unroll
      for (int kc = 0; kc < 2; kc++)
        vf[jd * 2 + kc] =
            *(const bf16x8_al*)(vtb + (size_t)(jd * 16 + lr) * SEQ + kt + kc * 32 + lq * 8);

    // S^T (keys x q): K A-frags straight from global; exp2; P^T pack (wave-private)
#pragma unroll
    for (int kb = 0; kb < 4; kb++) {
      const __bf16* kr = Kp + (size_t)(kt + kb * 16 + lr) * D_HEAD + lq * 8;
      bf16x8 kf0 = *(const bf16x8_al*)kr;
      bf16x8 kf1 = *(const bf16x8_al*)(kr + 32);
      floatx4 s = {};
      s = __builtin_amdgcn_mfma_f32_16x16x32_bf16(kf0, qf0, s, 0, 0, 0);
      s = __builtin_amdgcn_mfma_f32_16x16x32_bf16(kf1, qf1, s, 0, 0, 0);
      bf16x4 pv;
#pragma unroll
      for (int r = 0; r < 4; r++) {
        float p = __builtin_amdgcn_exp2f(s[r]);  // scale+log2e folded into K
        lsum += p;
        pv[r] = (__bf16)p;
      }
      // lane holds keys kb*16+lq*4+{0..3} for q=lr -> one b64 store
      int chunk = (kb * 2 + (lq >> 1)) ^ row7;
      *(bf16x4_al*)(plsw + lr * 64 + chunk * 8 + (lq & 1) * 4) = pv;
    }

    // O += P @ V : A-frag P[q=lr][key=kc*32+lq*8+j], B-frag Vt[d][key] (regs)
#pragma unroll
    for (int kc = 0; kc < 2; kc++) {
      int chunk = (kc * 4 + lq) ^ row7;
      bf16x8 pf = *(const bf16x8_al*)(plsw + lr * 64 + chunk * 8);
#pragma unroll
      for (int jd = 0; jd < 4; jd++)
        oacc[jd] = __builtin_amdgcn_mfma_f32_16x16x32_bf16(pf, vf[jd * 2 + kc], oacc[jd], 0, 0, 0);
    }
  }

  // reduce l across the 4 lanes sharing q=lr (lq groups)
  lsum += __shfl_xor(lsum, 16);
  lsum += __shfl_xor(lsum, 32);

  const int b = bh >> 4, h = bh & 15;
#pragma unroll
  for (int r = 0; r < 4; r++) {
    float linv = 1.0f / __shfl(lsum, lq * 4 + r);  // lane q_local holds l(q_local)
    int s = q0 + wave * 16 + lq * 4 + r;
#pragma unroll
    for (int jd = 0; jd < 4; jd++) {
      int d = jd * 16 + lr;
      O[((size_t)b * SEQ + s) * E_DIM + h * D_HEAD + d] = (__bf16)(oacc[jd][r] * linv);
    }
  }
}

// ---------------- launch ----------------
extern "C" void kernel_launch(void* const* d_in, const int* in_sizes, int n_in,
                              void* d_out, int out_size, void* d_ws, size_t ws_size,
                              hipStream_t stream) {
  const float* x  = (const float*)d_in[0];
  const float* Wi = (const float*)d_in[1];
  const float* Ai = (const float*)d_in[2];
  const float* Bi = (const float*)d_in[3];
  const float* Wo = (const float*)d_in[4];
  float* out = (float*)d_out;
  char* ws = (char*)d_ws;

  // workspace layout (bytes), ~49 MB
  __bf16* xb    = (__bf16*)(ws);                  // 4096x1024 bf16   8,388,608
  __bf16* wtot  = (__bf16*)(ws + 8388608);        // 3072x1024 bf16   6,291,456
  __bf16* binb  = (__bf16*)(ws + 14680064);       // 3072x128 bf16      786,432
  __bf16* aeffT = (__bf16*)(ws + 15466496);       // 1024x128 bf16      262,144
  __bf16* wob   = (__bf16*)(ws + 15728640);       // 1024x1024 bf16   2,097,152
  __bf16* qh    = (__bf16*)(ws + 17825792);       // [32][2048][64]   8,388,608
  __bf16* kh    = (__bf16*)(ws + 26214400);       // [32][2048][64]   8,388,608
  __bf16* vt    = (__bf16*)(ws + 34603008);       // [32][64][2048]   8,388,608
  __bf16* oh    = (__bf16*)(ws + 42991616);       // 4096x1024 bf16   8,388,608

  prep_all<<<8608, 256, 0, stream>>>(x, Wi, Bi, Ai, Wo, xb, wtot, binb, aeffT, wob);

  // wtot += (B_in @ Aeff)/128  (LoRA folded into weights; in-place on wtot)
  gemm_mfma<128, 128, 128, 128, 3><<<dim3(24, 8), 256, 0, stream>>>(
      binb, aeffT, nullptr, wtot, nullptr, nullptr);
  // qkv = xb @ wtot^T; Q,K -> head layout (K pre-scaled), V -> V^T directly
  gemm_mfma<128, 1024, 1024, 1024, 1><<<dim3(32, 24), 256, 0, stream>>>(
      xb, wtot, nullptr, qh, kh, vt);
  attn_kernel<<<dim3(32, 32), 256, 0, stream>>>(qh, kh, vt, oh);
  // final = O @ Wo^T (fp32 out), TM=64 -> 512 blocks (2/CU)
  gemm_mfma<64, 1024, 1024, 1024, 0><<<dim3(64, 8), 256, 0, stream>>>(
      oh, wob, out, nullptr, nullptr, nullptr);
}